// Round 10
// baseline (474.786 us; speedup 1.0000x reference)
//
#include <hip/hip_runtime.h>
#include <hip/hip_bf16.h>

#define D 128
#define LSTR 136   // bounce row stride (bf16): 128 + 8 pad

typedef __bf16 bf16x8 __attribute__((ext_vector_type(8)));
typedef __bf16 bf16x4 __attribute__((ext_vector_type(4)));
typedef float  f32x4  __attribute__((ext_vector_type(4)));
typedef float  f32x2  __attribute__((ext_vector_type(2)));

template <int ISBF>
__device__ __forceinline__ bf16x8 ld8(const void* p, size_t elem)
{
    if (ISBF) return *(const bf16x8*)((const __bf16*)p + elem);
    const f32x4* f = (const f32x4*)((const float*)p + elem);
    f32x4 lo = f[0], hi = f[1];
    bf16x8 r;
    r[0] = (__bf16)lo[0]; r[1] = (__bf16)lo[1]; r[2] = (__bf16)lo[2]; r[3] = (__bf16)lo[3];
    r[4] = (__bf16)hi[0]; r[5] = (__bf16)hi[1]; r[6] = (__bf16)hi[2]; r[7] = (__bf16)hi[3];
    return r;
}
template <int ISBF>
__device__ __forceinline__ float ldf(const void* p, size_t elem)
{
    return ISBF ? (float)((const __bf16*)p)[elem] : ((const float*)p)[elem];
}

// ---------------------------------------------------------------------------
// hist + fused dtype probe (block 0): 1 = bf16-packed, 0 = fp32.
// ---------------------------------------------------------------------------
__global__ __launch_bounds__(256) void hist_detect_kernel(
    const int* __restrict__ tgt, int* __restrict__ counts, int E,
    const unsigned int* __restrict__ w, int* __restrict__ flag)
{
    __shared__ int cnt[256];
    int e = blockIdx.x * 256 + threadIdx.x;
    if (e < E) atomicAdd(&counts[tgt[e]], 1);
    if (blockIdx.x == 0) {
        int c = 0;
#pragma unroll
        for (int i = 0; i < 4; ++i) {
            unsigned int v = w[threadIdx.x * 4 + i];
            unsigned int ex = (v >> 7) & 0xFF;
            if (ex >= 90 && ex <= 134) ++c;
        }
        cnt[threadIdx.x] = c;
        __syncthreads();
        for (int s = 128; s > 0; s >>= 1) {
            if (threadIdx.x < s) cnt[threadIdx.x] += cnt[threadIdx.x + s];
            __syncthreads();
        }
        if (threadIdx.x == 0) flag[0] = (cnt[0] > 614) ? 1 : 0;
    }
}

// ---------------------------------------------------------------------------
// CSR build
// ---------------------------------------------------------------------------
__global__ __launch_bounds__(256) void scan1_kernel(
    const int* __restrict__ counts, int* __restrict__ rowptr,
    int* __restrict__ bsum, int M)
{
    __shared__ int sh[256];
    int base = blockIdx.x * 1024 + threadIdx.x * 4;
    int v[4];
#pragma unroll
    for (int k = 0; k < 4; ++k)
        v[k] = (base + k < M) ? counts[base + k] : 0;
    int tot = v[0] + v[1] + v[2] + v[3];
    sh[threadIdx.x] = tot;
    __syncthreads();
    for (int off = 1; off < 256; off <<= 1) {
        int t = (threadIdx.x >= off) ? sh[threadIdx.x - off] : 0;
        __syncthreads();
        sh[threadIdx.x] += t;
        __syncthreads();
    }
    int run = sh[threadIdx.x] - tot;
#pragma unroll
    for (int k = 0; k < 4; ++k) {
        if (base + k < M) rowptr[base + k] = run;
        run += v[k];
    }
    if (threadIdx.x == 255) bsum[blockIdx.x] = sh[255];
}

__global__ __launch_bounds__(256) void scan3_kernel(
    int* __restrict__ rowptr, int* __restrict__ cursor,
    const int* __restrict__ bsum, int M, int E)
{
    int b = blockIdx.x;
    int o = 0;
    for (int i = 0; i < b; ++i) o += bsum[i];   // uniform, NB<=98, L2-hot
    int base = b * 1024 + threadIdx.x * 4;
#pragma unroll
    for (int k = 0; k < 4; ++k) {
        int i = base + k;
        if (i < M) {
            int r = rowptr[i] + o;
            rowptr[i] = r;
            cursor[i] = r;
        }
    }
    if (b == 0 && threadIdx.x == 0) rowptr[M] = E;
}

__global__ __launch_bounds__(256) void scatter_kernel(
    const int* __restrict__ deprel, const int* __restrict__ deparc,
    const int* __restrict__ src, const int* __restrict__ tgt,
    int* __restrict__ cursor, int2* __restrict__ recs, int E)
{
    int e = blockIdx.x * 256 + threadIdx.x;
    if (e >= E) return;
    int g = tgt[e];
    int pos = atomicAdd(&cursor[g], 1);
    recs[pos] = make_int2(src[e], (deprel[e] << 2) | deparc[e]);
}

// ---------------------------------------------------------------------------
// gemm1 v4: one block per (node-tile, t); grid = ntiles*4, XCD-remapped.
// LDS diet round 2: W staged in four 8KB K-quarters + 32-node bounce passes
// -> declared 8,704 B (runtime reports 2x declared; R6-R9 law) -> LDS cap 9,
// wave cap 8 -> 8 blocks/CU (was 4). Double-XOR swizzle keeps the 16-lane
// column reads conflict-free at 64B row stride.
// ---------------------------------------------------------------------------
template <int ISBF>
__device__ __forceinline__ void gemm1_body(
    const void* __restrict__ inp,
    const void* __restrict__ W0, const void* __restrict__ W1,
    const void* __restrict__ W2, const void* __restrict__ W3,
    const void* __restrict__ g0, const void* __restrict__ g1,
    const void* __restrict__ g2, const void* __restrict__ g3,
    const void* __restrict__ b_in, const void* __restrict__ b_out,
    const void* __restrict__ bg_in, const void* __restrict__ bg_out,
    __bf16* __restrict__ T, float* __restrict__ G,
    __bf16* __restrict__ Bz, float* __restrict__ Bgz, int M)
{
    __shared__ unsigned int shu[2176];   // 8,704 B = max(W-quarter 8KB, 32xLSTR bounce)
    __bf16* sh = (__bf16*)shu;

    // --- bijective XCD remap (m204): XCD k <- contiguous lin chunk ---
    const int nb  = gridDim.x;
    const int b   = blockIdx.x;
    const int xcd = b & 7, slot = b >> 3;
    const int q = nb >> 3, r = nb & 7;
    const int lin = (xcd < r) ? xcd * (q + 1) + slot
                              : r * (q + 1) + (xcd - r) * q + slot;
    const int tile = lin >> 2;
    const int t    = lin & 3;

    // --- bias tables (independent; first 101 physical blocks) ---
    if (blockIdx.x < 101 && threadIdx.x < 128) {
        int row = blockIdx.x;
        int tid = threadIdx.x;
        float v = 0.f, gv = 0.f;
        if (row < 50) {
            v  = ldf<ISBF>(b_in, (size_t)row * D + tid);
            gv = ldf<ISBF>(bg_in, row);
        } else if (row < 100) {
            int rr = row - 50;
            v  = ldf<ISBF>(b_out, (size_t)rr * D + tid);
            gv = ldf<ISBF>(bg_out, rr);
        }
        Bz[(size_t)row * D + tid] = (__bf16)v;
        if (tid == 0) Bgz[row] = gv;
    }

    const int wave = threadIdx.x >> 6;
    const int lane = threadIdx.x & 63;
    const int lrow = lane & 15;
    const int kgrp = lane >> 4;
    const int m_base = tile * 128 + wave * 32;

    int n0 = m_base + lrow;      if (n0 >= M) n0 = 0;   // clamped; stores guarded
    int n1 = m_base + 16 + lrow; if (n1 >= M) n1 = 0;

    // --- load inp fragments (reused for gate dot + MFMA) ---
    bf16x8 af0[4], af1[4];
#pragma unroll
    for (int ks = 0; ks < 4; ++ks) {
        const int k0 = ks * 32 + kgrp * 8;
        af0[ks] = ld8<ISBF>(inp, (size_t)n0 * D + k0);
        af1[ks] = ld8<ISBF>(inp, (size_t)n1 * D + k0);
    }

    // --- gate dot for THIS t only ---
    {
        const void* gs[4] = {g0, g1, g2, g3};
        const void* gt = gs[t];
        float s0 = 0.f, s1 = 0.f;
#pragma unroll
        for (int ks = 0; ks < 4; ++ks) {
            bf16x8 qv = ld8<ISBF>(gt, ks * 32 + kgrp * 8);
#pragma unroll
            for (int j = 0; j < 8; ++j) {
                float qf = (float)qv[j];
                s0 = fmaf((float)af0[ks][j], qf, s0);
                s1 = fmaf((float)af1[ks][j], qf, s1);
            }
        }
        s0 += __shfl_xor(s0, 16); s0 += __shfl_xor(s0, 32);
        s1 += __shfl_xor(s1, 16); s1 += __shfl_xor(s1, 32);
        if (kgrp == 0) {
            int nn0 = m_base + lrow;
            int nn1 = m_base + 16 + lrow;
            if (nn0 < M) G[(size_t)t * M + nn0] = s0;
            if (nn1 < M) G[(size_t)t * M + nn1] = s1;
        }
    }

    // --- MFMA over four W K-quarters (8KB LDS each) ---
    const void* Ws[4] = {W0, W1, W2, W3};
    const void* W = Ws[t];

    f32x4 acc[2][8];
#pragma unroll
    for (int i = 0; i < 2; ++i)
#pragma unroll
        for (int j = 0; j < 8; ++j)
            acc[i][j] = (f32x4){0.f, 0.f, 0.f, 0.f};

#pragma unroll
    for (int h = 0; h < 4; ++h) {
        // stage W[:, h*32 : h*32+32): 128 rows x 4 slots of 16B, dbl-XOR swizzle
#pragma unroll
        for (int i = 0; i < 2; ++i) {
            int idx = threadIdx.x + 256 * i;   // 0..511
            int f = idx >> 2;
            int s = idx & 3;
            int sp = s ^ (f & 3) ^ ((f >> 2) & 3);
            bf16x8 v = ld8<ISBF>(W, (size_t)f * D + h * 32 + s * 8);
            *(bf16x8*)(sh + f * 32 + sp * 8) = v;
        }
        __syncthreads();

#pragma unroll
        for (int ft = 0; ft < 8; ++ft) {
            int f = ft * 16 + lrow;
            int sp = kgrp ^ (f & 3) ^ ((f >> 2) & 3);
            bf16x8 wf = *(const bf16x8*)(sh + f * 32 + sp * 8);
            acc[0][ft] = __builtin_amdgcn_mfma_f32_16x16x32_bf16(wf, af0[h], acc[0][ft], 0, 0, 0);
            acc[1][ft] = __builtin_amdgcn_mfma_f32_16x16x32_bf16(wf, af1[h], acc[1][ft], 0, 0, 0);
        }
        __syncthreads();
    }

    // --- bounce + coalesced copy-out, 32 nodes (one wave's acc) per pass ---
#pragma unroll
    for (int p = 0; p < 4; ++p) {
        if (wave == p) {
#pragma unroll
            for (int nt = 0; nt < 2; ++nt) {
#pragma unroll
                for (int ft = 0; ft < 8; ++ft) {
                    int f0 = ft * 16 + kgrp * 4;
                    f32x4 v = acc[nt][ft];
                    bf16x4 w4;
                    w4[0] = (__bf16)v[0]; w4[1] = (__bf16)v[1];
                    w4[2] = (__bf16)v[2]; w4[3] = (__bf16)v[3];
                    *(bf16x4*)(sh + (nt * 16 + lrow) * LSTR + f0) = w4;
                }
            }
        }
        __syncthreads();
#pragma unroll
        for (int s = 0; s < 2; ++s) {
            int idx = s * 256 + threadIdx.x;
            int node = idx >> 4;                 // 0..31
            int seg  = idx & 15;
            bf16x8 v = *(const bf16x8*)(sh + node * LSTR + seg * 8);
            int gn = tile * 128 + p * 32 + node;
            if (gn < M)
                *(bf16x8*)(T + (size_t)gn * (4 * D) + t * D + seg * 8) = v;
        }
        if (p < 3) __syncthreads();
    }
}

__global__ __launch_bounds__(256, 8) void gemm1_kernel(
    const void* __restrict__ inp,
    const void* __restrict__ W0, const void* __restrict__ W1,
    const void* __restrict__ W2, const void* __restrict__ W3,
    const void* __restrict__ g0, const void* __restrict__ g1,
    const void* __restrict__ g2, const void* __restrict__ g3,
    const void* __restrict__ b_in, const void* __restrict__ b_out,
    const void* __restrict__ bg_in, const void* __restrict__ bg_out,
    __bf16* __restrict__ T, float* __restrict__ G,
    __bf16* __restrict__ Bz, float* __restrict__ Bgz, int M,
    const int* __restrict__ flag)
{
    if (flag[0]) gemm1_body<1>(inp, W0, W1, W2, W3, g0, g1, g2, g3,
                               b_in, b_out, bg_in, bg_out, T, G, Bz, Bgz, M);
    else         gemm1_body<0>(inp, W0, W1, W2, W3, g0, g1, g2, g3,
                               b_in, b_out, bg_in, bg_out, T, G, Bz, Bgz, M);
}

// ---------------------------------------------------------------------------
// edge_agg2: out[g] = sum_e gate_e * (T[src_e][t_e] + Bz[bidx_e]).
// 16 lanes/node, natural order, 2-deep pipeline, scalar fmaf.
// ---------------------------------------------------------------------------
template <int ISBF>
__device__ __forceinline__ void edge_agg2_body(
    const __bf16* __restrict__ T, const float* __restrict__ G,
    const __bf16* __restrict__ Bz, const float* __restrict__ Bgz,
    const int* __restrict__ rowptr, const int2* __restrict__ recs,
    void* __restrict__ out, int M)
{
    const int g = blockIdx.x * 16 + (threadIdx.x >> 4);
    if (g >= M) return;
    const int lane16 = threadIdx.x & 15;
    const int dd = lane16 * 8;

    const int beg = rowptr[g], end = rowptr[g + 1];
    const int n = end - beg;

    float acc[8];
#pragma unroll
    for (int k = 0; k < 8; ++k) acc[k] = 0.f;

    // 2-deep pipeline
    bf16x8 tv_c = {}, bz_c = {};
    float gp_c = 0.f, bg_c = 0.f;
    int2 rec_n = make_int2(0, 0);

    auto issue = [&](int2 rec) {
        int t = rec.y & 3;
        int r = rec.y >> 2;
        int bidx = (t < 2) ? t * 50 + r : 100;
        gp_c = G[(size_t)t * M + rec.x];
        bg_c = Bgz[bidx];
        tv_c = *(const bf16x8*)(T + (size_t)rec.x * (4 * D) + t * D + dd);
        bz_c = *(const bf16x8*)(Bz + (size_t)bidx * D + dd);
    };

    if (n > 0) {
        issue(recs[beg]);
        if (n > 1) rec_n = recs[beg + 1];
    }

    for (int e = 0; e < n; ++e) {
        const bf16x8 tv = tv_c, bz = bz_c;
        const float gp = gp_c, bg = bg_c;

        if (e + 1 < n) {                 // issue next edge's loads now
            issue(rec_n);
            if (e + 2 < n) rec_n = recs[beg + e + 2];
        }

        const float gate = 1.f / (1.f + __expf(-(gp + bg)));
#pragma unroll
        for (int k = 0; k < 8; ++k)
            acc[k] = fmaf(gate, (float)tv[k] + (float)bz[k], acc[k]);
    }

    if (ISBF) {
        bf16x8 w;
#pragma unroll
        for (int k = 0; k < 8; ++k) w[k] = (__bf16)acc[k];
        __builtin_nontemporal_store(w, (bf16x8*)((__bf16*)out + (size_t)g * D + dd));
    } else {
        f32x4 lo = {acc[0], acc[1], acc[2], acc[3]};
        f32x4 hi = {acc[4], acc[5], acc[6], acc[7]};
        __builtin_nontemporal_store(lo, (f32x4*)((float*)out + (size_t)g * D + dd));
        __builtin_nontemporal_store(hi, (f32x4*)((float*)out + (size_t)g * D + dd + 4));
    }
}

__global__ __launch_bounds__(256) void edge_agg2_kernel(
    const __bf16* __restrict__ T, const float* __restrict__ G,
    const __bf16* __restrict__ Bz, const float* __restrict__ Bgz,
    const int* __restrict__ rowptr, const int2* __restrict__ recs,
    void* __restrict__ out, int M, const int* __restrict__ flag)
{
    if (flag[0]) edge_agg2_body<1>(T, G, Bz, Bgz, rowptr, recs, out, M);
    else         edge_agg2_body<0>(T, G, Bz, Bgz, rowptr, recs, out, M);
}

__global__ void sentinel_kernel(__bf16* o, int n)
{
    int i = blockIdx.x * blockDim.x + threadIdx.x;
    if (i < n) o[i] = (__bf16)12345.0f;
}

static inline size_t align256(size_t x) { return (x + 255) & ~(size_t)255; }

extern "C" void kernel_launch(void* const* d_in, const int* in_sizes, int n_in,
                              void* d_out, int out_size, void* d_ws, size_t ws_size,
                              hipStream_t stream)
{
    const void* inp       = d_in[0];
    const int*  deprel    = (const int*)d_in[1];
    const int*  deparc    = (const int*)d_in[2];
    const int*  eidx      = (const int*)d_in[3];
    const void* V_in      = d_in[4];
    const void* b_in      = d_in[5];
    const void* V_in_g    = d_in[6];
    const void* b_in_g    = d_in[7];
    const void* V_out     = d_in[8];
    const void* b_out     = d_in[9];
    const void* V_out_g   = d_in[10];
    const void* b_out_g   = d_in[11];
    const void* W_self    = d_in[12];
    const void* W_self_g  = d_in[13];
    const void* W_norel   = d_in[14];
    const void* W_norel_g = d_in[15];

    const int M = in_sizes[0] / D;   // 100000
    const int E = in_sizes[1];       // 600000
    const int* src = eidx;
    const int* tgt = eidx + E;
    const int NB = (M + 1023) / 1024;

    size_t off = 0;
    size_t o_flag   = off; off = align256(off + sizeof(int));
    size_t o_T      = off; off = align256(off + (size_t)M * 4 * D * sizeof(__bf16));
    size_t o_G      = off; off = align256(off + (size_t)4 * M * sizeof(float));
    size_t o_counts = off; off = align256(off + (size_t)M * sizeof(int));
    size_t o_rowptr = off; off = align256(off + (size_t)(M + 1) * sizeof(int));
    size_t o_cursor = off; off = align256(off + (size_t)M * sizeof(int));
    size_t o_bsum   = off; off = align256(off + (size_t)NB * sizeof(int));
    size_t o_recs   = off; off = align256(off + (size_t)E * sizeof(int2));
    size_t o_Bz     = off; off = align256(off + (size_t)101 * D * sizeof(__bf16));
    size_t o_Bgz    = off; off = align256(off + (size_t)101 * sizeof(float));

    if (off > ws_size) {
        sentinel_kernel<<<(out_size + 255) / 256, 256, 0, stream>>>(
            (__bf16*)d_out, out_size);
        return;
    }

    int*    flag   = (int*)((char*)d_ws + o_flag);
    __bf16* T      = (__bf16*)((char*)d_ws + o_T);
    float*  Gbuf   = (float*)((char*)d_ws + o_G);
    int*    counts = (int*)((char*)d_ws + o_counts);
    int*    rowptr = (int*)((char*)d_ws + o_rowptr);
    int*    cursor = (int*)((char*)d_ws + o_cursor);
    int*    bsum   = (int*)((char*)d_ws + o_bsum);
    int2*   recs   = (int2*)((char*)d_ws + o_recs);
    __bf16* Bz     = (__bf16*)((char*)d_ws + o_Bz);
    float*  Bgz    = (float*)((char*)d_ws + o_Bgz);

    // CSR build (detect fused into hist block 0)
    hipMemsetAsync(counts, 0, (size_t)M * sizeof(int), stream);
    hist_detect_kernel<<<(E + 255) / 256, 256, 0, stream>>>(
        tgt, counts, E, (const unsigned int*)inp, flag);
    scan1_kernel<<<NB, 256, 0, stream>>>(counts, rowptr, bsum, M);
    scan3_kernel<<<NB, 256, 0, stream>>>(rowptr, cursor, bsum, M, E);
    scatter_kernel<<<(E + 255) / 256, 256, 0, stream>>>(deprel, deparc, src, tgt,
                                                        cursor, recs, E);

    // transform + gates + bias tables (fused, split grid: tile x t, XCD-remapped)
    const int ntiles = (M + 127) / 128;
    gemm1_kernel<<<ntiles * 4, 256, 0, stream>>>(
        inp, V_in, V_out, W_self, W_norel,
        V_in_g, V_out_g, W_self_g, W_norel_g,
        b_in, b_out, b_in_g, b_out_g, T, Gbuf, Bz, Bgz, M, flag);

    // gather-aggregate directly to output
    edge_agg2_kernel<<<(M + 15) / 16, 256, 0, stream>>>(
        T, Gbuf, Bz, Bgz, rowptr, recs, d_out, M, flag);
}

// Round 11
// 352.115 us; speedup vs baseline: 1.3484x; 1.3484x over previous
//
#include <hip/hip_runtime.h>
#include <hip/hip_bf16.h>

#define D 128
#define LSTR 136   // bounce row stride (bf16): 128 + 8 pad

typedef __bf16 bf16x8 __attribute__((ext_vector_type(8)));
typedef __bf16 bf16x4 __attribute__((ext_vector_type(4)));
typedef float  f32x4  __attribute__((ext_vector_type(4)));
typedef float  f32x2  __attribute__((ext_vector_type(2)));

template <int ISBF>
__device__ __forceinline__ bf16x8 ld8(const void* p, size_t elem)
{
    if (ISBF) return *(const bf16x8*)((const __bf16*)p + elem);
    const f32x4* f = (const f32x4*)((const float*)p + elem);
    f32x4 lo = f[0], hi = f[1];
    bf16x8 r;
    r[0] = (__bf16)lo[0]; r[1] = (__bf16)lo[1]; r[2] = (__bf16)lo[2]; r[3] = (__bf16)lo[3];
    r[4] = (__bf16)hi[0]; r[5] = (__bf16)hi[1]; r[6] = (__bf16)hi[2]; r[7] = (__bf16)hi[3];
    return r;
}
template <int ISBF>
__device__ __forceinline__ float ldf(const void* p, size_t elem)
{
    return ISBF ? (float)((const __bf16*)p)[elem] : ((const float*)p)[elem];
}

// ---------------------------------------------------------------------------
// hist + fused dtype probe (block 0): 1 = bf16-packed, 0 = fp32.
// ---------------------------------------------------------------------------
__global__ __launch_bounds__(256) void hist_detect_kernel(
    const int* __restrict__ tgt, int* __restrict__ counts, int E,
    const unsigned int* __restrict__ w, int* __restrict__ flag)
{
    __shared__ int cnt[256];
    int e = blockIdx.x * 256 + threadIdx.x;
    if (e < E) atomicAdd(&counts[tgt[e]], 1);
    if (blockIdx.x == 0) {
        int c = 0;
#pragma unroll
        for (int i = 0; i < 4; ++i) {
            unsigned int v = w[threadIdx.x * 4 + i];
            unsigned int ex = (v >> 7) & 0xFF;
            if (ex >= 90 && ex <= 134) ++c;
        }
        cnt[threadIdx.x] = c;
        __syncthreads();
        for (int s = 128; s > 0; s >>= 1) {
            if (threadIdx.x < s) cnt[threadIdx.x] += cnt[threadIdx.x + s];
            __syncthreads();
        }
        if (threadIdx.x == 0) flag[0] = (cnt[0] > 614) ? 1 : 0;
    }
}

// ---------------------------------------------------------------------------
// CSR build
// ---------------------------------------------------------------------------
__global__ __launch_bounds__(256) void scan1_kernel(
    const int* __restrict__ counts, int* __restrict__ rowptr,
    int* __restrict__ bsum, int M)
{
    __shared__ int sh[256];
    int base = blockIdx.x * 1024 + threadIdx.x * 4;
    int v[4];
#pragma unroll
    for (int k = 0; k < 4; ++k)
        v[k] = (base + k < M) ? counts[base + k] : 0;
    int tot = v[0] + v[1] + v[2] + v[3];
    sh[threadIdx.x] = tot;
    __syncthreads();
    for (int off = 1; off < 256; off <<= 1) {
        int t = (threadIdx.x >= off) ? sh[threadIdx.x - off] : 0;
        __syncthreads();
        sh[threadIdx.x] += t;
        __syncthreads();
    }
    int run = sh[threadIdx.x] - tot;
#pragma unroll
    for (int k = 0; k < 4; ++k) {
        if (base + k < M) rowptr[base + k] = run;
        run += v[k];
    }
    if (threadIdx.x == 255) bsum[blockIdx.x] = sh[255];
}

__global__ __launch_bounds__(256) void scan3_kernel(
    int* __restrict__ rowptr, int* __restrict__ cursor,
    const int* __restrict__ bsum, int M, int E)
{
    int b = blockIdx.x;
    int o = 0;
    for (int i = 0; i < b; ++i) o += bsum[i];   // uniform, NB<=98, L2-hot
    int base = b * 1024 + threadIdx.x * 4;
#pragma unroll
    for (int k = 0; k < 4; ++k) {
        int i = base + k;
        if (i < M) {
            int r = rowptr[i] + o;
            rowptr[i] = r;
            cursor[i] = r;
        }
    }
    if (b == 0 && threadIdx.x == 0) rowptr[M] = E;
}

__global__ __launch_bounds__(256) void scatter_kernel(
    const int* __restrict__ deprel, const int* __restrict__ deparc,
    const int* __restrict__ src, const int* __restrict__ tgt,
    int* __restrict__ cursor, int2* __restrict__ recs, int E)
{
    int e = blockIdx.x * 256 + threadIdx.x;
    if (e >= E) return;
    int g = tgt[e];
    int pos = atomicAdd(&cursor[g], 1);
    recs[pos] = make_int2(src[e], (deprel[e] << 2) | deparc[e]);
}

// ---------------------------------------------------------------------------
// gemm1 v5: one block per (node-tile, t); grid = ntiles*4, XCD-remapped.
// W consumed DIRECTLY from global (L2-hot 32KB/t; ~128KB L2 reads per block)
// -> no W-LDS staging, barriers 7 -> 3. LDS holds only the 64-node bounce
// tile (declared 17,408 B -> reported 2x -> 4 blocks/CU, same as R9).
// __launch_bounds__(256,4): VGPR cap 128, no spill (R10 lesson: (256,8)
// forced 64-VGPR cap -> acc spilled to scratch, 6x WRITE_SIZE, 4x slower).
// ---------------------------------------------------------------------------
template <int ISBF>
__device__ __forceinline__ void gemm1_body(
    const void* __restrict__ inp,
    const void* __restrict__ W0, const void* __restrict__ W1,
    const void* __restrict__ W2, const void* __restrict__ W3,
    const void* __restrict__ g0, const void* __restrict__ g1,
    const void* __restrict__ g2, const void* __restrict__ g3,
    const void* __restrict__ b_in, const void* __restrict__ b_out,
    const void* __restrict__ bg_in, const void* __restrict__ bg_out,
    __bf16* __restrict__ T, float* __restrict__ G,
    __bf16* __restrict__ Bz, float* __restrict__ Bgz, int M)
{
    __shared__ unsigned int shu[4352];   // 17,408 B: 64 x LSTR bf16 bounce tile
    __bf16* sh = (__bf16*)shu;

    // --- bijective XCD remap (m204): XCD k <- contiguous lin chunk ---
    const int nb  = gridDim.x;
    const int b   = blockIdx.x;
    const int xcd = b & 7, slot = b >> 3;
    const int q = nb >> 3, r = nb & 7;
    const int lin = (xcd < r) ? xcd * (q + 1) + slot
                              : r * (q + 1) + (xcd - r) * q + slot;
    const int tile = lin >> 2;
    const int t    = lin & 3;

    // --- bias tables (independent; first 101 physical blocks) ---
    if (blockIdx.x < 101 && threadIdx.x < 128) {
        int row = blockIdx.x;
        int tid = threadIdx.x;
        float v = 0.f, gv = 0.f;
        if (row < 50) {
            v  = ldf<ISBF>(b_in, (size_t)row * D + tid);
            gv = ldf<ISBF>(bg_in, row);
        } else if (row < 100) {
            int rr = row - 50;
            v  = ldf<ISBF>(b_out, (size_t)rr * D + tid);
            gv = ldf<ISBF>(bg_out, rr);
        }
        Bz[(size_t)row * D + tid] = (__bf16)v;
        if (tid == 0) Bgz[row] = gv;
    }

    const int wave = threadIdx.x >> 6;
    const int lane = threadIdx.x & 63;
    const int lrow = lane & 15;
    const int kgrp = lane >> 4;
    const int m_base = tile * 128 + wave * 32;

    int n0 = m_base + lrow;      if (n0 >= M) n0 = 0;   // clamped; stores guarded
    int n1 = m_base + 16 + lrow; if (n1 >= M) n1 = 0;

    // --- load inp fragments (reused for gate dot + MFMA) ---
    bf16x8 af0[4], af1[4];
#pragma unroll
    for (int ks = 0; ks < 4; ++ks) {
        const int k0 = ks * 32 + kgrp * 8;
        af0[ks] = ld8<ISBF>(inp, (size_t)n0 * D + k0);
        af1[ks] = ld8<ISBF>(inp, (size_t)n1 * D + k0);
    }

    // --- gate dot for THIS t only ---
    {
        const void* gs[4] = {g0, g1, g2, g3};
        const void* gt = gs[t];
        float s0 = 0.f, s1 = 0.f;
#pragma unroll
        for (int ks = 0; ks < 4; ++ks) {
            bf16x8 qv = ld8<ISBF>(gt, ks * 32 + kgrp * 8);
#pragma unroll
            for (int j = 0; j < 8; ++j) {
                float qf = (float)qv[j];
                s0 = fmaf((float)af0[ks][j], qf, s0);
                s1 = fmaf((float)af1[ks][j], qf, s1);
            }
        }
        s0 += __shfl_xor(s0, 16); s0 += __shfl_xor(s0, 32);
        s1 += __shfl_xor(s1, 16); s1 += __shfl_xor(s1, 32);
        if (kgrp == 0) {
            int nn0 = m_base + lrow;
            int nn1 = m_base + 16 + lrow;
            if (nn0 < M) G[(size_t)t * M + nn0] = s0;
            if (nn1 < M) G[(size_t)t * M + nn1] = s1;
        }
    }

    // --- MFMA: wf fragments straight from global (L2-hot), no barriers ---
    const void* Ws[4] = {W0, W1, W2, W3};
    const void* W = Ws[t];

    f32x4 acc[2][8];
#pragma unroll
    for (int i = 0; i < 2; ++i)
#pragma unroll
        for (int j = 0; j < 8; ++j)
            acc[i][j] = (f32x4){0.f, 0.f, 0.f, 0.f};

#pragma unroll
    for (int ks = 0; ks < 4; ++ks) {
        const int kc = ks * 32 + kgrp * 8;       // k-column of this lane's frag
#pragma unroll
        for (int ft = 0; ft < 8; ++ft) {
            int f = ft * 16 + lrow;
            bf16x8 wf = ld8<ISBF>(W, (size_t)f * D + kc);
            acc[0][ft] = __builtin_amdgcn_mfma_f32_16x16x32_bf16(wf, af0[ks], acc[0][ft], 0, 0, 0);
            acc[1][ft] = __builtin_amdgcn_mfma_f32_16x16x32_bf16(wf, af1[ks], acc[1][ft], 0, 0, 0);
        }
    }

    // --- bounce + coalesced copy-out, 64 nodes (2 waves) per pass ---
#pragma unroll
    for (int bh = 0; bh < 2; ++bh) {
        if ((wave >> 1) == bh) {                 // waves 2bh, 2bh+1
            int nlb = (wave & 1) * 32;
#pragma unroll
            for (int nt = 0; nt < 2; ++nt) {
#pragma unroll
                for (int ft = 0; ft < 8; ++ft) {
                    int f0 = ft * 16 + kgrp * 4;
                    f32x4 v = acc[nt][ft];
                    bf16x4 w4;
                    w4[0] = (__bf16)v[0]; w4[1] = (__bf16)v[1];
                    w4[2] = (__bf16)v[2]; w4[3] = (__bf16)v[3];
                    *(bf16x4*)(sh + (nlb + nt * 16 + lrow) * LSTR + f0) = w4;
                }
            }
        }
        __syncthreads();
#pragma unroll
        for (int s = 0; s < 4; ++s) {
            int idx = s * 256 + threadIdx.x;
            int node = idx >> 4;                 // 0..63
            int seg  = idx & 15;
            bf16x8 v = *(const bf16x8*)(sh + node * LSTR + seg * 8);
            int gn = tile * 128 + bh * 64 + node;
            if (gn < M)
                *(bf16x8*)(T + (size_t)gn * (4 * D) + t * D + seg * 8) = v;
        }
        if (bh == 0) __syncthreads();
    }
}

__global__ __launch_bounds__(256, 4) void gemm1_kernel(
    const void* __restrict__ inp,
    const void* __restrict__ W0, const void* __restrict__ W1,
    const void* __restrict__ W2, const void* __restrict__ W3,
    const void* __restrict__ g0, const void* __restrict__ g1,
    const void* __restrict__ g2, const void* __restrict__ g3,
    const void* __restrict__ b_in, const void* __restrict__ b_out,
    const void* __restrict__ bg_in, const void* __restrict__ bg_out,
    __bf16* __restrict__ T, float* __restrict__ G,
    __bf16* __restrict__ Bz, float* __restrict__ Bgz, int M,
    const int* __restrict__ flag)
{
    if (flag[0]) gemm1_body<1>(inp, W0, W1, W2, W3, g0, g1, g2, g3,
                               b_in, b_out, bg_in, bg_out, T, G, Bz, Bgz, M);
    else         gemm1_body<0>(inp, W0, W1, W2, W3, g0, g1, g2, g3,
                               b_in, b_out, bg_in, bg_out, T, G, Bz, Bgz, M);
}

// ---------------------------------------------------------------------------
// edge_agg2: out[g] = sum_e gate_e * (T[src_e][t_e] + Bz[bidx_e]).
// 16 lanes/node, natural order, 2-deep pipeline, scalar fmaf.
// ---------------------------------------------------------------------------
template <int ISBF>
__device__ __forceinline__ void edge_agg2_body(
    const __bf16* __restrict__ T, const float* __restrict__ G,
    const __bf16* __restrict__ Bz, const float* __restrict__ Bgz,
    const int* __restrict__ rowptr, const int2* __restrict__ recs,
    void* __restrict__ out, int M)
{
    const int g = blockIdx.x * 16 + (threadIdx.x >> 4);
    if (g >= M) return;
    const int lane16 = threadIdx.x & 15;
    const int dd = lane16 * 8;

    const int beg = rowptr[g], end = rowptr[g + 1];
    const int n = end - beg;

    float acc[8];
#pragma unroll
    for (int k = 0; k < 8; ++k) acc[k] = 0.f;

    // 2-deep pipeline
    bf16x8 tv_c = {}, bz_c = {};
    float gp_c = 0.f, bg_c = 0.f;
    int2 rec_n = make_int2(0, 0);

    auto issue = [&](int2 rec) {
        int t = rec.y & 3;
        int r = rec.y >> 2;
        int bidx = (t < 2) ? t * 50 + r : 100;
        gp_c = G[(size_t)t * M + rec.x];
        bg_c = Bgz[bidx];
        tv_c = *(const bf16x8*)(T + (size_t)rec.x * (4 * D) + t * D + dd);
        bz_c = *(const bf16x8*)(Bz + (size_t)bidx * D + dd);
    };

    if (n > 0) {
        issue(recs[beg]);
        if (n > 1) rec_n = recs[beg + 1];
    }

    for (int e = 0; e < n; ++e) {
        const bf16x8 tv = tv_c, bz = bz_c;
        const float gp = gp_c, bg = bg_c;

        if (e + 1 < n) {                 // issue next edge's loads now
            issue(rec_n);
            if (e + 2 < n) rec_n = recs[beg + e + 2];
        }

        const float gate = 1.f / (1.f + __expf(-(gp + bg)));
#pragma unroll
        for (int k = 0; k < 8; ++k)
            acc[k] = fmaf(gate, (float)tv[k] + (float)bz[k], acc[k]);
    }

    if (ISBF) {
        bf16x8 w;
#pragma unroll
        for (int k = 0; k < 8; ++k) w[k] = (__bf16)acc[k];
        __builtin_nontemporal_store(w, (bf16x8*)((__bf16*)out + (size_t)g * D + dd));
    } else {
        f32x4 lo = {acc[0], acc[1], acc[2], acc[3]};
        f32x4 hi = {acc[4], acc[5], acc[6], acc[7]};
        __builtin_nontemporal_store(lo, (f32x4*)((float*)out + (size_t)g * D + dd));
        __builtin_nontemporal_store(hi, (f32x4*)((float*)out + (size_t)g * D + dd + 4));
    }
}

__global__ __launch_bounds__(256) void edge_agg2_kernel(
    const __bf16* __restrict__ T, const float* __restrict__ G,
    const __bf16* __restrict__ Bz, const float* __restrict__ Bgz,
    const int* __restrict__ rowptr, const int2* __restrict__ recs,
    void* __restrict__ out, int M, const int* __restrict__ flag)
{
    if (flag[0]) edge_agg2_body<1>(T, G, Bz, Bgz, rowptr, recs, out, M);
    else         edge_agg2_body<0>(T, G, Bz, Bgz, rowptr, recs, out, M);
}

__global__ void sentinel_kernel(__bf16* o, int n)
{
    int i = blockIdx.x * blockDim.x + threadIdx.x;
    if (i < n) o[i] = (__bf16)12345.0f;
}

static inline size_t align256(size_t x) { return (x + 255) & ~(size_t)255; }

extern "C" void kernel_launch(void* const* d_in, const int* in_sizes, int n_in,
                              void* d_out, int out_size, void* d_ws, size_t ws_size,
                              hipStream_t stream)
{
    const void* inp       = d_in[0];
    const int*  deprel    = (const int*)d_in[1];
    const int*  deparc    = (const int*)d_in[2];
    const int*  eidx      = (const int*)d_in[3];
    const void* V_in      = d_in[4];
    const void* b_in      = d_in[5];
    const void* V_in_g    = d_in[6];
    const void* b_in_g    = d_in[7];
    const void* V_out     = d_in[8];
    const void* b_out     = d_in[9];
    const void* V_out_g   = d_in[10];
    const void* b_out_g   = d_in[11];
    const void* W_self    = d_in[12];
    const void* W_self_g  = d_in[13];
    const void* W_norel   = d_in[14];
    const void* W_norel_g = d_in[15];

    const int M = in_sizes[0] / D;   // 100000
    const int E = in_sizes[1];       // 600000
    const int* src = eidx;
    const int* tgt = eidx + E;
    const int NB = (M + 1023) / 1024;

    size_t off = 0;
    size_t o_flag   = off; off = align256(off + sizeof(int));
    size_t o_T      = off; off = align256(off + (size_t)M * 4 * D * sizeof(__bf16));
    size_t o_G      = off; off = align256(off + (size_t)4 * M * sizeof(float));
    size_t o_counts = off; off = align256(off + (size_t)M * sizeof(int));
    size_t o_rowptr = off; off = align256(off + (size_t)(M + 1) * sizeof(int));
    size_t o_cursor = off; off = align256(off + (size_t)M * sizeof(int));
    size_t o_bsum   = off; off = align256(off + (size_t)NB * sizeof(int));
    size_t o_recs   = off; off = align256(off + (size_t)E * sizeof(int2));
    size_t o_Bz     = off; off = align256(off + (size_t)101 * D * sizeof(__bf16));
    size_t o_Bgz    = off; off = align256(off + (size_t)101 * sizeof(float));

    if (off > ws_size) {
        sentinel_kernel<<<(out_size + 255) / 256, 256, 0, stream>>>(
            (__bf16*)d_out, out_size);
        return;
    }

    int*    flag   = (int*)((char*)d_ws + o_flag);
    __bf16* T      = (__bf16*)((char*)d_ws + o_T);
    float*  Gbuf   = (float*)((char*)d_ws + o_G);
    int*    counts = (int*)((char*)d_ws + o_counts);
    int*    rowptr = (int*)((char*)d_ws + o_rowptr);
    int*    cursor = (int*)((char*)d_ws + o_cursor);
    int*    bsum   = (int*)((char*)d_ws + o_bsum);
    int2*   recs   = (int2*)((char*)d_ws + o_recs);
    __bf16* Bz     = (__bf16*)((char*)d_ws + o_Bz);
    float*  Bgz    = (float*)((char*)d_ws + o_Bgz);

    // CSR build (detect fused into hist block 0)
    hipMemsetAsync(counts, 0, (size_t)M * sizeof(int), stream);
    hist_detect_kernel<<<(E + 255) / 256, 256, 0, stream>>>(
        tgt, counts, E, (const unsigned int*)inp, flag);
    scan1_kernel<<<NB, 256, 0, stream>>>(counts, rowptr, bsum, M);
    scan3_kernel<<<NB, 256, 0, stream>>>(rowptr, cursor, bsum, M, E);
    scatter_kernel<<<(E + 255) / 256, 256, 0, stream>>>(deprel, deparc, src, tgt,
                                                        cursor, recs, E);

    // transform + gates + bias tables (fused, split grid: tile x t, XCD-remapped)
    const int ntiles = (M + 127) / 128;
    gemm1_kernel<<<ntiles * 4, 256, 0, stream>>>(
        inp, V_in, V_out, W_self, W_norel,
        V_in_g, V_out_g, W_self_g, W_norel_g,
        b_in, b_out, b_in_g, b_out_g, T, Gbuf, Bz, Bgz, M, flag);

    // gather-aggregate directly to output
    edge_agg2_kernel<<<(M + 15) / 16, 256, 0, stream>>>(
        T, Gbuf, Bz, Bgz, rowptr, recs, d_out, M, flag);
}

// Round 12
// 279.074 us; speedup vs baseline: 1.7013x; 1.2617x over previous
//
#include <hip/hip_runtime.h>
#include <hip/hip_bf16.h>

#define D 128
#define LSTR 136   // bounce row stride (bf16): 128 + 8 pad

typedef __bf16 bf16x8 __attribute__((ext_vector_type(8)));
typedef __bf16 bf16x4 __attribute__((ext_vector_type(4)));
typedef float  f32x4  __attribute__((ext_vector_type(4)));
typedef float  f32x2  __attribute__((ext_vector_type(2)));

template <int ISBF>
__device__ __forceinline__ bf16x8 ld8(const void* p, size_t elem)
{
    if (ISBF) return *(const bf16x8*)((const __bf16*)p + elem);
    const f32x4* f = (const f32x4*)((const float*)p + elem);
    f32x4 lo = f[0], hi = f[1];
    bf16x8 r;
    r[0] = (__bf16)lo[0]; r[1] = (__bf16)lo[1]; r[2] = (__bf16)lo[2]; r[3] = (__bf16)lo[3];
    r[4] = (__bf16)hi[0]; r[5] = (__bf16)hi[1]; r[6] = (__bf16)hi[2]; r[7] = (__bf16)hi[3];
    return r;
}
template <int ISBF>
__device__ __forceinline__ float ldf(const void* p, size_t elem)
{
    return ISBF ? (float)((const __bf16*)p)[elem] : ((const float*)p)[elem];
}

// ---------------------------------------------------------------------------
// hist + fused dtype probe (block 0): 1 = bf16-packed, 0 = fp32.
// ---------------------------------------------------------------------------
__global__ __launch_bounds__(256) void hist_detect_kernel(
    const int* __restrict__ tgt, int* __restrict__ counts, int E,
    const unsigned int* __restrict__ w, int* __restrict__ flag)
{
    __shared__ int cnt[256];
    int e = blockIdx.x * 256 + threadIdx.x;
    if (e < E) atomicAdd(&counts[tgt[e]], 1);
    if (blockIdx.x == 0) {
        int c = 0;
#pragma unroll
        for (int i = 0; i < 4; ++i) {
            unsigned int v = w[threadIdx.x * 4 + i];
            unsigned int ex = (v >> 7) & 0xFF;
            if (ex >= 90 && ex <= 134) ++c;
        }
        cnt[threadIdx.x] = c;
        __syncthreads();
        for (int s = 128; s > 0; s >>= 1) {
            if (threadIdx.x < s) cnt[threadIdx.x] += cnt[threadIdx.x + s];
            __syncthreads();
        }
        if (threadIdx.x == 0) flag[0] = (cnt[0] > 614) ? 1 : 0;
    }
}

// ---------------------------------------------------------------------------
// CSR build
// ---------------------------------------------------------------------------
__global__ __launch_bounds__(256) void scan1_kernel(
    const int* __restrict__ counts, int* __restrict__ rowptr,
    int* __restrict__ bsum, int M)
{
    __shared__ int sh[256];
    int base = blockIdx.x * 1024 + threadIdx.x * 4;
    int v[4];
#pragma unroll
    for (int k = 0; k < 4; ++k)
        v[k] = (base + k < M) ? counts[base + k] : 0;
    int tot = v[0] + v[1] + v[2] + v[3];
    sh[threadIdx.x] = tot;
    __syncthreads();
    for (int off = 1; off < 256; off <<= 1) {
        int t = (threadIdx.x >= off) ? sh[threadIdx.x - off] : 0;
        __syncthreads();
        sh[threadIdx.x] += t;
        __syncthreads();
    }
    int run = sh[threadIdx.x] - tot;
#pragma unroll
    for (int k = 0; k < 4; ++k) {
        if (base + k < M) rowptr[base + k] = run;
        run += v[k];
    }
    if (threadIdx.x == 255) bsum[blockIdx.x] = sh[255];
}

__global__ __launch_bounds__(256) void scan3_kernel(
    int* __restrict__ rowptr, int* __restrict__ cursor,
    const int* __restrict__ bsum, int M, int E)
{
    int b = blockIdx.x;
    int o = 0;
    for (int i = 0; i < b; ++i) o += bsum[i];   // uniform, NB<=98, L2-hot
    int base = b * 1024 + threadIdx.x * 4;
#pragma unroll
    for (int k = 0; k < 4; ++k) {
        int i = base + k;
        if (i < M) {
            int r = rowptr[i] + o;
            rowptr[i] = r;
            cursor[i] = r;
        }
    }
    if (b == 0 && threadIdx.x == 0) rowptr[M] = E;
}

__global__ __launch_bounds__(256) void scatter_kernel(
    const int* __restrict__ deprel, const int* __restrict__ deparc,
    const int* __restrict__ src, const int* __restrict__ tgt,
    int* __restrict__ cursor, int2* __restrict__ recs, int E)
{
    int e = blockIdx.x * 256 + threadIdx.x;
    if (e >= E) return;
    int g = tgt[e];
    int pos = atomicAdd(&cursor[g], 1);
    recs[pos] = make_int2(src[e], (deprel[e] << 2) | deparc[e]);
}

// ---------------------------------------------------------------------------
// gemm1 (R9-proven, 64.7us): one block per (node-tile, t); grid = ntiles*4,
// XCD-remapped; W staged in two 16KB K-halves (LDS); 64-node bounce passes.
// Declared LDS 17,408 B (reported 2x) -> 4 blocks/CU. (256,4): VGPR 64, no
// spill. [R10: (256,8) wave-cap -> spill, 4x slower. R11: W direct from
// global -> 256B-stride lanes, 64 lines/load, issue-rate bound, 2.2x slower.]
// ---------------------------------------------------------------------------
template <int ISBF>
__device__ __forceinline__ void gemm1_body(
    const void* __restrict__ inp,
    const void* __restrict__ W0, const void* __restrict__ W1,
    const void* __restrict__ W2, const void* __restrict__ W3,
    const void* __restrict__ g0, const void* __restrict__ g1,
    const void* __restrict__ g2, const void* __restrict__ g3,
    const void* __restrict__ b_in, const void* __restrict__ b_out,
    const void* __restrict__ bg_in, const void* __restrict__ bg_out,
    __bf16* __restrict__ T, float* __restrict__ G,
    __bf16* __restrict__ Bz, float* __restrict__ Bgz, int M)
{
    __shared__ unsigned int shu[4352];   // 17,408 B = max(W-half 16KB, 64x136 bounce)
    __bf16* sh = (__bf16*)shu;

    // --- bijective XCD remap (m204): XCD k <- contiguous lin chunk ---
    const int nb  = gridDim.x;
    const int b   = blockIdx.x;
    const int xcd = b & 7, slot = b >> 3;
    const int q = nb >> 3, r = nb & 7;
    const int lin = (xcd < r) ? xcd * (q + 1) + slot
                              : r * (q + 1) + (xcd - r) * q + slot;
    const int tile = lin >> 2;
    const int t    = lin & 3;

    // --- bias tables (independent; first 101 physical blocks) ---
    if (blockIdx.x < 101 && threadIdx.x < 128) {
        int row = blockIdx.x;
        int tid = threadIdx.x;
        float v = 0.f, gv = 0.f;
        if (row < 50) {
            v  = ldf<ISBF>(b_in, (size_t)row * D + tid);
            gv = ldf<ISBF>(bg_in, row);
        } else if (row < 100) {
            int rr = row - 50;
            v  = ldf<ISBF>(b_out, (size_t)rr * D + tid);
            gv = ldf<ISBF>(bg_out, rr);
        }
        Bz[(size_t)row * D + tid] = (__bf16)v;
        if (tid == 0) Bgz[row] = gv;
    }

    const int wave = threadIdx.x >> 6;
    const int lane = threadIdx.x & 63;
    const int lrow = lane & 15;
    const int kgrp = lane >> 4;
    const int m_base = tile * 128 + wave * 32;

    int n0 = m_base + lrow;      if (n0 >= M) n0 = 0;   // clamped; stores guarded
    int n1 = m_base + 16 + lrow; if (n1 >= M) n1 = 0;

    // --- load inp fragments (reused for gate dot + MFMA) ---
    bf16x8 af0[4], af1[4];
#pragma unroll
    for (int ks = 0; ks < 4; ++ks) {
        const int k0 = ks * 32 + kgrp * 8;
        af0[ks] = ld8<ISBF>(inp, (size_t)n0 * D + k0);
        af1[ks] = ld8<ISBF>(inp, (size_t)n1 * D + k0);
    }

    // --- gate dot for THIS t only ---
    {
        const void* gs[4] = {g0, g1, g2, g3};
        const void* gt = gs[t];
        float s0 = 0.f, s1 = 0.f;
#pragma unroll
        for (int ks = 0; ks < 4; ++ks) {
            bf16x8 qv = ld8<ISBF>(gt, ks * 32 + kgrp * 8);
#pragma unroll
            for (int j = 0; j < 8; ++j) {
                float qf = (float)qv[j];
                s0 = fmaf((float)af0[ks][j], qf, s0);
                s1 = fmaf((float)af1[ks][j], qf, s1);
            }
        }
        s0 += __shfl_xor(s0, 16); s0 += __shfl_xor(s0, 32);
        s1 += __shfl_xor(s1, 16); s1 += __shfl_xor(s1, 32);
        if (kgrp == 0) {
            int nn0 = m_base + lrow;
            int nn1 = m_base + 16 + lrow;
            if (nn0 < M) G[(size_t)t * M + nn0] = s0;
            if (nn1 < M) G[(size_t)t * M + nn1] = s1;
        }
    }

    // --- MFMA over two W K-halves (16KB LDS each) ---
    const void* Ws[4] = {W0, W1, W2, W3};
    const void* W = Ws[t];

    f32x4 acc[2][8];
#pragma unroll
    for (int i = 0; i < 2; ++i)
#pragma unroll
        for (int j = 0; j < 8; ++j)
            acc[i][j] = (f32x4){0.f, 0.f, 0.f, 0.f};

#pragma unroll
    for (int h = 0; h < 2; ++h) {
        // stage W[:, h*64 : h*64+64]: 128 rows x 8 slots of 16B, XOR-swizzled
#pragma unroll
        for (int i = 0; i < 4; ++i) {
            int idx = threadIdx.x + 256 * i;
            int f = idx >> 3;
            int s = idx & 7;
            int sp = s ^ (f & 7);
            bf16x8 v = ld8<ISBF>(W, (size_t)f * D + h * 64 + s * 8);
            *(bf16x8*)(sh + f * 64 + sp * 8) = v;
        }
        __syncthreads();

#pragma unroll
        for (int kl = 0; kl < 2; ++kl) {
            const int ks = h * 2 + kl;           // static (h,kl unrolled)
            const int slot = kl * 4 + kgrp;      // 0..7
#pragma unroll
            for (int ft = 0; ft < 8; ++ft) {
                int f = ft * 16 + lrow;
                int sp = slot ^ (f & 7);
                bf16x8 wf = *(const bf16x8*)(sh + f * 64 + sp * 8);
                acc[0][ft] = __builtin_amdgcn_mfma_f32_16x16x32_bf16(wf, af0[ks], acc[0][ft], 0, 0, 0);
                acc[1][ft] = __builtin_amdgcn_mfma_f32_16x16x32_bf16(wf, af1[ks], acc[1][ft], 0, 0, 0);
            }
        }
        __syncthreads();
    }

    // --- bounce + coalesced copy-out, 64 nodes per pass ---
#pragma unroll
    for (int bh = 0; bh < 2; ++bh) {
        if ((wave >> 1) == bh) {                 // waves owning nodes [bh*64, bh*64+64)
            int nlb = (wave & 1) * 32;
#pragma unroll
            for (int nt = 0; nt < 2; ++nt) {
#pragma unroll
                for (int ft = 0; ft < 8; ++ft) {
                    int f0 = ft * 16 + kgrp * 4;
                    f32x4 v = acc[nt][ft];
                    bf16x4 w4;
                    w4[0] = (__bf16)v[0]; w4[1] = (__bf16)v[1];
                    w4[2] = (__bf16)v[2]; w4[3] = (__bf16)v[3];
                    *(bf16x4*)(sh + (nlb + nt * 16 + lrow) * LSTR + f0) = w4;
                }
            }
        }
        __syncthreads();
#pragma unroll
        for (int s = 0; s < 4; ++s) {
            int idx = s * 256 + threadIdx.x;
            int node = idx >> 4;                 // 0..63
            int seg  = idx & 15;
            bf16x8 v = *(const bf16x8*)(sh + node * LSTR + seg * 8);
            int gn = tile * 128 + bh * 64 + node;
            if (gn < M)
                *(bf16x8*)(T + (size_t)gn * (4 * D) + t * D + seg * 8) = v;
        }
        if (bh == 0) __syncthreads();
    }
}

__global__ __launch_bounds__(256, 4) void gemm1_kernel(
    const void* __restrict__ inp,
    const void* __restrict__ W0, const void* __restrict__ W1,
    const void* __restrict__ W2, const void* __restrict__ W3,
    const void* __restrict__ g0, const void* __restrict__ g1,
    const void* __restrict__ g2, const void* __restrict__ g3,
    const void* __restrict__ b_in, const void* __restrict__ b_out,
    const void* __restrict__ bg_in, const void* __restrict__ bg_out,
    __bf16* __restrict__ T, float* __restrict__ G,
    __bf16* __restrict__ Bz, float* __restrict__ Bgz, int M,
    const int* __restrict__ flag)
{
    if (flag[0]) gemm1_body<1>(inp, W0, W1, W2, W3, g0, g1, g2, g3,
                               b_in, b_out, bg_in, bg_out, T, G, Bz, Bgz, M);
    else         gemm1_body<0>(inp, W0, W1, W2, W3, g0, g1, g2, g3,
                               b_in, b_out, bg_in, bg_out, T, G, Bz, Bgz, M);
}

// ---------------------------------------------------------------------------
// edge_agg2: out[g] = sum_e gate_e * (T[src_e][t_e] + Bz[bidx_e]).
// 16 lanes/node, natural order, 3-deep pipeline (deg~Poisson(6): one more
// latency-cover slot for 85% of edges), scalar fmaf.
// ---------------------------------------------------------------------------
template <int ISBF>
__device__ __forceinline__ void edge_agg2_body(
    const __bf16* __restrict__ T, const float* __restrict__ G,
    const __bf16* __restrict__ Bz, const float* __restrict__ Bgz,
    const int* __restrict__ rowptr, const int2* __restrict__ recs,
    void* __restrict__ out, int M)
{
    const int g = blockIdx.x * 16 + (threadIdx.x >> 4);
    if (g >= M) return;
    const int lane16 = threadIdx.x & 15;
    const int dd = lane16 * 8;

    const int beg = rowptr[g], end = rowptr[g + 1];
    const int n = end - beg;

    float acc[8];
#pragma unroll
    for (int k = 0; k < 8; ++k) acc[k] = 0.f;

    // 3-deep pipeline: stage0 (ready), stage1 (in flight), rec for stage2
    bf16x8 tv0 = {}, bz0 = {}, tv1 = {}, bz1 = {};
    float gp0 = 0.f, bg0 = 0.f, gp1 = 0.f, bg1 = 0.f;
    int2 r2 = make_int2(0, 0);

    auto issue = [&](int2 rec, bf16x8& tv, bf16x8& bz, float& gp, float& bg) {
        int t = rec.y & 3;
        int r = rec.y >> 2;
        int bidx = (t < 2) ? t * 50 + r : 100;
        gp = G[(size_t)t * M + rec.x];
        bg = Bgz[bidx];
        tv = *(const bf16x8*)(T + (size_t)rec.x * (4 * D) + t * D + dd);
        bz = *(const bf16x8*)(Bz + (size_t)bidx * D + dd);
    };

    if (n > 0) issue(recs[beg], tv0, bz0, gp0, bg0);
    if (n > 1) issue(recs[beg + 1], tv1, bz1, gp1, bg1);
    if (n > 2) r2 = recs[beg + 2];

    for (int e = 0; e < n; ++e) {
        const bf16x8 tv = tv0, bz = bz0;
        const float gp = gp0, bg = bg0;

        // shift + issue next
        tv0 = tv1; bz0 = bz1; gp0 = gp1; bg0 = bg1;
        if (e + 2 < n) {
            issue(r2, tv1, bz1, gp1, bg1);
            if (e + 3 < n) r2 = recs[beg + e + 3];
        }

        const float gate = 1.f / (1.f + __expf(-(gp + bg)));
#pragma unroll
        for (int k = 0; k < 8; ++k)
            acc[k] = fmaf(gate, (float)tv[k] + (float)bz[k], acc[k]);
    }

    if (ISBF) {
        bf16x8 w;
#pragma unroll
        for (int k = 0; k < 8; ++k) w[k] = (__bf16)acc[k];
        __builtin_nontemporal_store(w, (bf16x8*)((__bf16*)out + (size_t)g * D + dd));
    } else {
        f32x4 lo = {acc[0], acc[1], acc[2], acc[3]};
        f32x4 hi = {acc[4], acc[5], acc[6], acc[7]};
        __builtin_nontemporal_store(lo, (f32x4*)((float*)out + (size_t)g * D + dd));
        __builtin_nontemporal_store(hi, (f32x4*)((float*)out + (size_t)g * D + dd + 4));
    }
}

__global__ __launch_bounds__(256) void edge_agg2_kernel(
    const __bf16* __restrict__ T, const float* __restrict__ G,
    const __bf16* __restrict__ Bz, const float* __restrict__ Bgz,
    const int* __restrict__ rowptr, const int2* __restrict__ recs,
    void* __restrict__ out, int M, const int* __restrict__ flag)
{
    if (flag[0]) edge_agg2_body<1>(T, G, Bz, Bgz, rowptr, recs, out, M);
    else         edge_agg2_body<0>(T, G, Bz, Bgz, rowptr, recs, out, M);
}

__global__ void sentinel_kernel(__bf16* o, int n)
{
    int i = blockIdx.x * blockDim.x + threadIdx.x;
    if (i < n) o[i] = (__bf16)12345.0f;
}

static inline size_t align256(size_t x) { return (x + 255) & ~(size_t)255; }

extern "C" void kernel_launch(void* const* d_in, const int* in_sizes, int n_in,
                              void* d_out, int out_size, void* d_ws, size_t ws_size,
                              hipStream_t stream)
{
    const void* inp       = d_in[0];
    const int*  deprel    = (const int*)d_in[1];
    const int*  deparc    = (const int*)d_in[2];
    const int*  eidx      = (const int*)d_in[3];
    const void* V_in      = d_in[4];
    const void* b_in      = d_in[5];
    const void* V_in_g    = d_in[6];
    const void* b_in_g    = d_in[7];
    const void* V_out     = d_in[8];
    const void* b_out     = d_in[9];
    const void* V_out_g   = d_in[10];
    const void* b_out_g   = d_in[11];
    const void* W_self    = d_in[12];
    const void* W_self_g  = d_in[13];
    const void* W_norel   = d_in[14];
    const void* W_norel_g = d_in[15];

    const int M = in_sizes[0] / D;   // 100000
    const int E = in_sizes[1];       // 600000
    const int* src = eidx;
    const int* tgt = eidx + E;
    const int NB = (M + 1023) / 1024;

    size_t off = 0;
    size_t o_flag   = off; off = align256(off + sizeof(int));
    size_t o_T      = off; off = align256(off + (size_t)M * 4 * D * sizeof(__bf16));
    size_t o_G      = off; off = align256(off + (size_t)4 * M * sizeof(float));
    size_t o_counts = off; off = align256(off + (size_t)M * sizeof(int));
    size_t o_rowptr = off; off = align256(off + (size_t)(M + 1) * sizeof(int));
    size_t o_cursor = off; off = align256(off + (size_t)M * sizeof(int));
    size_t o_bsum   = off; off = align256(off + (size_t)NB * sizeof(int));
    size_t o_recs   = off; off = align256(off + (size_t)E * sizeof(int2));
    size_t o_Bz     = off; off = align256(off + (size_t)101 * D * sizeof(__bf16));
    size_t o_Bgz    = off; off = align256(off + (size_t)101 * sizeof(float));

    if (off > ws_size) {
        sentinel_kernel<<<(out_size + 255) / 256, 256, 0, stream>>>(
            (__bf16*)d_out, out_size);
        return;
    }

    int*    flag   = (int*)((char*)d_ws + o_flag);
    __bf16* T      = (__bf16*)((char*)d_ws + o_T);
    float*  Gbuf   = (float*)((char*)d_ws + o_G);
    int*    counts = (int*)((char*)d_ws + o_counts);
    int*    rowptr = (int*)((char*)d_ws + o_rowptr);
    int*    cursor = (int*)((char*)d_ws + o_cursor);
    int*    bsum   = (int*)((char*)d_ws + o_bsum);
    int2*   recs   = (int2*)((char*)d_ws + o_recs);
    __bf16* Bz     = (__bf16*)((char*)d_ws + o_Bz);
    float*  Bgz    = (float*)((char*)d_ws + o_Bgz);

    // CSR build (detect fused into hist block 0)
    hipMemsetAsync(counts, 0, (size_t)M * sizeof(int), stream);
    hist_detect_kernel<<<(E + 255) / 256, 256, 0, stream>>>(
        tgt, counts, E, (const unsigned int*)inp, flag);
    scan1_kernel<<<NB, 256, 0, stream>>>(counts, rowptr, bsum, M);
    scan3_kernel<<<NB, 256, 0, stream>>>(rowptr, cursor, bsum, M, E);
    scatter_kernel<<<(E + 255) / 256, 256, 0, stream>>>(deprel, deparc, src, tgt,
                                                        cursor, recs, E);

    // transform + gates + bias tables (fused, split grid: tile x t, XCD-remapped)
    const int ntiles = (M + 127) / 128;
    gemm1_kernel<<<ntiles * 4, 256, 0, stream>>>(
        inp, V_in, V_out, W_self, W_norel,
        V_in_g, V_out_g, W_self_g, W_norel_g,
        b_in, b_out, b_in_g, b_out_g, T, Gbuf, Bz, Bgz, M, flag);

    // gather-aggregate directly to output
    edge_agg2_kernel<<<(M + 15) / 16, 256, 0, stream>>>(
        T, Gbuf, Bz, Bgz, rowptr, recs, d_out, M, flag);
}

// Round 13
// 274.463 us; speedup vs baseline: 1.7299x; 1.0168x over previous
//
#include <hip/hip_runtime.h>
#include <hip/hip_bf16.h>

#define D 128
#define LSTR 136   // bounce row stride (bf16): 128 + 8 pad

typedef __bf16 bf16x8 __attribute__((ext_vector_type(8)));
typedef __bf16 bf16x4 __attribute__((ext_vector_type(4)));
typedef float  f32x4  __attribute__((ext_vector_type(4)));
typedef float  f32x2  __attribute__((ext_vector_type(2)));

template <int ISBF>
__device__ __forceinline__ bf16x8 ld8(const void* p, size_t elem)
{
    if (ISBF) return *(const bf16x8*)((const __bf16*)p + elem);
    const f32x4* f = (const f32x4*)((const float*)p + elem);
    f32x4 lo = f[0], hi = f[1];
    bf16x8 r;
    r[0] = (__bf16)lo[0]; r[1] = (__bf16)lo[1]; r[2] = (__bf16)lo[2]; r[3] = (__bf16)lo[3];
    r[4] = (__bf16)hi[0]; r[5] = (__bf16)hi[1]; r[6] = (__bf16)hi[2]; r[7] = (__bf16)hi[3];
    return r;
}
template <int ISBF>
__device__ __forceinline__ float ldf(const void* p, size_t elem)
{
    return ISBF ? (float)((const __bf16*)p)[elem] : ((const float*)p)[elem];
}

// ---------------------------------------------------------------------------
// hist + fused dtype probe (block 0): 1 = bf16-packed, 0 = fp32.
// ---------------------------------------------------------------------------
__global__ __launch_bounds__(256) void hist_detect_kernel(
    const int* __restrict__ tgt, int* __restrict__ counts, int E,
    const unsigned int* __restrict__ w, int* __restrict__ flag)
{
    __shared__ int cnt[256];
    int e = blockIdx.x * 256 + threadIdx.x;
    if (e < E) atomicAdd(&counts[tgt[e]], 1);
    if (blockIdx.x == 0) {
        int c = 0;
#pragma unroll
        for (int i = 0; i < 4; ++i) {
            unsigned int v = w[threadIdx.x * 4 + i];
            unsigned int ex = (v >> 7) & 0xFF;
            if (ex >= 90 && ex <= 134) ++c;
        }
        cnt[threadIdx.x] = c;
        __syncthreads();
        for (int s = 128; s > 0; s >>= 1) {
            if (threadIdx.x < s) cnt[threadIdx.x] += cnt[threadIdx.x + s];
            __syncthreads();
        }
        if (threadIdx.x == 0) flag[0] = (cnt[0] > 614) ? 1 : 0;
    }
}

// ---------------------------------------------------------------------------
// CSR build (scans)
// ---------------------------------------------------------------------------
__global__ __launch_bounds__(256) void scan1_kernel(
    const int* __restrict__ counts, int* __restrict__ rowptr,
    int* __restrict__ bsum, int M)
{
    __shared__ int sh[256];
    int base = blockIdx.x * 1024 + threadIdx.x * 4;
    int v[4];
#pragma unroll
    for (int k = 0; k < 4; ++k)
        v[k] = (base + k < M) ? counts[base + k] : 0;
    int tot = v[0] + v[1] + v[2] + v[3];
    sh[threadIdx.x] = tot;
    __syncthreads();
    for (int off = 1; off < 256; off <<= 1) {
        int t = (threadIdx.x >= off) ? sh[threadIdx.x - off] : 0;
        __syncthreads();
        sh[threadIdx.x] += t;
        __syncthreads();
    }
    int run = sh[threadIdx.x] - tot;
#pragma unroll
    for (int k = 0; k < 4; ++k) {
        if (base + k < M) rowptr[base + k] = run;
        run += v[k];
    }
    if (threadIdx.x == 255) bsum[blockIdx.x] = sh[255];
}

__global__ __launch_bounds__(256) void scan3_kernel(
    int* __restrict__ rowptr, int* __restrict__ cursor,
    const int* __restrict__ bsum, int M, int E)
{
    int b = blockIdx.x;
    int o = 0;
    for (int i = 0; i < b; ++i) o += bsum[i];   // uniform, NB<=98, L2-hot
    int base = b * 1024 + threadIdx.x * 4;
#pragma unroll
    for (int k = 0; k < 4; ++k) {
        int i = base + k;
        if (i < M) {
            int r = rowptr[i] + o;
            rowptr[i] = r;
            cursor[i] = r;
        }
    }
    if (b == 0 && threadIdx.x == 0) rowptr[M] = E;
}

// ---------------------------------------------------------------------------
// FUSED scatter || gemm1. Blocks < NSb: CSR scatter (independent of gemm1;
// returns before any barrier). Blocks >= NSb: R9-proven gemm1 (64.7us) with
// pb = blockIdx.x - NSb. NSb is a multiple of 8 so the gemm1 sub-grid keeps
// physical-XCD alignment for the bijective remap. Scatter (~25-35us of
// random-atomic work) hides under gemm1's execution -> sum becomes max.
// [R10: (256,8) wave-cap -> spill. R11: W direct from global -> issue-rate
// bound. Both reverted; W staged in two 16KB K-halves, 4 blocks/CU.]
// ---------------------------------------------------------------------------
template <int ISBF>
__device__ __forceinline__ void gemm1_body(
    int pb, int nbg,
    const void* __restrict__ inp,
    const void* __restrict__ W0, const void* __restrict__ W1,
    const void* __restrict__ W2, const void* __restrict__ W3,
    const void* __restrict__ g0, const void* __restrict__ g1,
    const void* __restrict__ g2, const void* __restrict__ g3,
    const void* __restrict__ b_in, const void* __restrict__ b_out,
    const void* __restrict__ bg_in, const void* __restrict__ bg_out,
    __bf16* __restrict__ T, float* __restrict__ G,
    __bf16* __restrict__ Bz, float* __restrict__ Bgz, int M,
    __bf16* sh)
{
    // --- bijective XCD remap (m204): XCD k <- contiguous lin chunk ---
    const int xcd = pb & 7, slot = pb >> 3;
    const int q = nbg >> 3, r = nbg & 7;
    const int lin = (xcd < r) ? xcd * (q + 1) + slot
                              : r * (q + 1) + (xcd - r) * q + slot;
    const int tile = lin >> 2;
    const int t    = lin & 3;

    // --- bias tables (independent; first 101 gemm1 blocks) ---
    if (pb < 101 && threadIdx.x < 128) {
        int row = pb;
        int tid = threadIdx.x;
        float v = 0.f, gv = 0.f;
        if (row < 50) {
            v  = ldf<ISBF>(b_in, (size_t)row * D + tid);
            gv = ldf<ISBF>(bg_in, row);
        } else if (row < 100) {
            int rr = row - 50;
            v  = ldf<ISBF>(b_out, (size_t)rr * D + tid);
            gv = ldf<ISBF>(bg_out, rr);
        }
        Bz[(size_t)row * D + tid] = (__bf16)v;
        if (tid == 0) Bgz[row] = gv;
    }

    const int wave = threadIdx.x >> 6;
    const int lane = threadIdx.x & 63;
    const int lrow = lane & 15;
    const int kgrp = lane >> 4;
    const int m_base = tile * 128 + wave * 32;

    int n0 = m_base + lrow;      if (n0 >= M) n0 = 0;   // clamped; stores guarded
    int n1 = m_base + 16 + lrow; if (n1 >= M) n1 = 0;

    // --- load inp fragments (reused for gate dot + MFMA) ---
    bf16x8 af0[4], af1[4];
#pragma unroll
    for (int ks = 0; ks < 4; ++ks) {
        const int k0 = ks * 32 + kgrp * 8;
        af0[ks] = ld8<ISBF>(inp, (size_t)n0 * D + k0);
        af1[ks] = ld8<ISBF>(inp, (size_t)n1 * D + k0);
    }

    // --- gate dot for THIS t only ---
    {
        const void* gs[4] = {g0, g1, g2, g3};
        const void* gt = gs[t];
        float s0 = 0.f, s1 = 0.f;
#pragma unroll
        for (int ks = 0; ks < 4; ++ks) {
            bf16x8 qv = ld8<ISBF>(gt, ks * 32 + kgrp * 8);
#pragma unroll
            for (int j = 0; j < 8; ++j) {
                float qf = (float)qv[j];
                s0 = fmaf((float)af0[ks][j], qf, s0);
                s1 = fmaf((float)af1[ks][j], qf, s1);
            }
        }
        s0 += __shfl_xor(s0, 16); s0 += __shfl_xor(s0, 32);
        s1 += __shfl_xor(s1, 16); s1 += __shfl_xor(s1, 32);
        if (kgrp == 0) {
            int nn0 = m_base + lrow;
            int nn1 = m_base + 16 + lrow;
            if (nn0 < M) G[(size_t)t * M + nn0] = s0;
            if (nn1 < M) G[(size_t)t * M + nn1] = s1;
        }
    }

    // --- MFMA over two W K-halves (16KB LDS each) ---
    const void* Ws[4] = {W0, W1, W2, W3};
    const void* W = Ws[t];

    f32x4 acc[2][8];
#pragma unroll
    for (int i = 0; i < 2; ++i)
#pragma unroll
        for (int j = 0; j < 8; ++j)
            acc[i][j] = (f32x4){0.f, 0.f, 0.f, 0.f};

#pragma unroll
    for (int h = 0; h < 2; ++h) {
        // stage W[:, h*64 : h*64+64]: 128 rows x 8 slots of 16B, XOR-swizzled
#pragma unroll
        for (int i = 0; i < 4; ++i) {
            int idx = threadIdx.x + 256 * i;
            int f = idx >> 3;
            int s = idx & 7;
            int sp = s ^ (f & 7);
            bf16x8 v = ld8<ISBF>(W, (size_t)f * D + h * 64 + s * 8);
            *(bf16x8*)(sh + f * 64 + sp * 8) = v;
        }
        __syncthreads();

#pragma unroll
        for (int kl = 0; kl < 2; ++kl) {
            const int ks = h * 2 + kl;           // static (h,kl unrolled)
            const int slot = kl * 4 + kgrp;      // 0..7
#pragma unroll
            for (int ft = 0; ft < 8; ++ft) {
                int f = ft * 16 + lrow;
                int sp = slot ^ (f & 7);
                bf16x8 wf = *(const bf16x8*)(sh + f * 64 + sp * 8);
                acc[0][ft] = __builtin_amdgcn_mfma_f32_16x16x32_bf16(wf, af0[ks], acc[0][ft], 0, 0, 0);
                acc[1][ft] = __builtin_amdgcn_mfma_f32_16x16x32_bf16(wf, af1[ks], acc[1][ft], 0, 0, 0);
            }
        }
        __syncthreads();
    }

    // --- bounce + coalesced copy-out, 64 nodes per pass ---
#pragma unroll
    for (int bh = 0; bh < 2; ++bh) {
        if ((wave >> 1) == bh) {                 // waves owning nodes [bh*64, bh*64+64)
            int nlb = (wave & 1) * 32;
#pragma unroll
            for (int nt = 0; nt < 2; ++nt) {
#pragma unroll
                for (int ft = 0; ft < 8; ++ft) {
                    int f0 = ft * 16 + kgrp * 4;
                    f32x4 v = acc[nt][ft];
                    bf16x4 w4;
                    w4[0] = (__bf16)v[0]; w4[1] = (__bf16)v[1];
                    w4[2] = (__bf16)v[2]; w4[3] = (__bf16)v[3];
                    *(bf16x4*)(sh + (nlb + nt * 16 + lrow) * LSTR + f0) = w4;
                }
            }
        }
        __syncthreads();
#pragma unroll
        for (int s = 0; s < 4; ++s) {
            int idx = s * 256 + threadIdx.x;
            int node = idx >> 4;                 // 0..63
            int seg  = idx & 15;
            bf16x8 v = *(const bf16x8*)(sh + node * LSTR + seg * 8);
            int gn = tile * 128 + bh * 64 + node;
            if (gn < M)
                *(bf16x8*)(T + (size_t)gn * (4 * D) + t * D + seg * 8) = v;
        }
        if (bh == 0) __syncthreads();
    }
}

__global__ __launch_bounds__(256, 4) void scatter_gemm1_kernel(
    // scatter path
    const int* __restrict__ deprel, const int* __restrict__ deparc,
    const int* __restrict__ srcA, const int* __restrict__ tgtA,
    int* __restrict__ cursor, int2* __restrict__ recs, int E, int NSb,
    // gemm1 path
    const void* __restrict__ inp,
    const void* __restrict__ W0, const void* __restrict__ W1,
    const void* __restrict__ W2, const void* __restrict__ W3,
    const void* __restrict__ g0, const void* __restrict__ g1,
    const void* __restrict__ g2, const void* __restrict__ g3,
    const void* __restrict__ b_in, const void* __restrict__ b_out,
    const void* __restrict__ bg_in, const void* __restrict__ bg_out,
    __bf16* __restrict__ T, float* __restrict__ G,
    __bf16* __restrict__ Bz, float* __restrict__ Bgz, int M,
    const int* __restrict__ flag)
{
    __shared__ unsigned int shu[4352];   // 17,408 B = max(W-half 16KB, 64x136 bounce)

    if ((int)blockIdx.x < NSb) {
        int e = blockIdx.x * 256 + threadIdx.x;
        if (e < E) {
            int g = tgtA[e];
            int pos = atomicAdd(&cursor[g], 1);
            recs[pos] = make_int2(srcA[e], (deprel[e] << 2) | deparc[e]);
        }
        return;   // before any barrier: whole block exits, no sync hazard
    }

    const int pb  = blockIdx.x - NSb;
    const int nbg = gridDim.x - NSb;
    if (flag[0]) gemm1_body<1>(pb, nbg, inp, W0, W1, W2, W3, g0, g1, g2, g3,
                               b_in, b_out, bg_in, bg_out, T, G, Bz, Bgz, M,
                               (__bf16*)shu);
    else         gemm1_body<0>(pb, nbg, inp, W0, W1, W2, W3, g0, g1, g2, g3,
                               b_in, b_out, bg_in, bg_out, T, G, Bz, Bgz, M,
                               (__bf16*)shu);
}

// ---------------------------------------------------------------------------
// edge_agg2: out[g] = sum_e gate_e * (T[src_e][t_e] + Bz[bidx_e]).
// 16 lanes/node, natural order, 2-deep pipeline (R9-proven; 3-deep was
// neutral-to-negative in R12), scalar fmaf.
// ---------------------------------------------------------------------------
template <int ISBF>
__device__ __forceinline__ void edge_agg2_body(
    const __bf16* __restrict__ T, const float* __restrict__ G,
    const __bf16* __restrict__ Bz, const float* __restrict__ Bgz,
    const int* __restrict__ rowptr, const int2* __restrict__ recs,
    void* __restrict__ out, int M)
{
    const int g = blockIdx.x * 16 + (threadIdx.x >> 4);
    if (g >= M) return;
    const int lane16 = threadIdx.x & 15;
    const int dd = lane16 * 8;

    const int beg = rowptr[g], end = rowptr[g + 1];
    const int n = end - beg;

    float acc[8];
#pragma unroll
    for (int k = 0; k < 8; ++k) acc[k] = 0.f;

    // 2-deep pipeline
    bf16x8 tv_c = {}, bz_c = {};
    float gp_c = 0.f, bg_c = 0.f;
    int2 rec_n = make_int2(0, 0);

    auto issue = [&](int2 rec) {
        int t = rec.y & 3;
        int r = rec.y >> 2;
        int bidx = (t < 2) ? t * 50 + r : 100;
        gp_c = G[(size_t)t * M + rec.x];
        bg_c = Bgz[bidx];
        tv_c = *(const bf16x8*)(T + (size_t)rec.x * (4 * D) + t * D + dd);
        bz_c = *(const bf16x8*)(Bz + (size_t)bidx * D + dd);
    };

    if (n > 0) {
        issue(recs[beg]);
        if (n > 1) rec_n = recs[beg + 1];
    }

    for (int e = 0; e < n; ++e) {
        const bf16x8 tv = tv_c, bz = bz_c;
        const float gp = gp_c, bg = bg_c;

        if (e + 1 < n) {                 // issue next edge's loads now
            issue(rec_n);
            if (e + 2 < n) rec_n = recs[beg + e + 2];
        }

        const float gate = 1.f / (1.f + __expf(-(gp + bg)));
#pragma unroll
        for (int k = 0; k < 8; ++k)
            acc[k] = fmaf(gate, (float)tv[k] + (float)bz[k], acc[k]);
    }

    if (ISBF) {
        bf16x8 w;
#pragma unroll
        for (int k = 0; k < 8; ++k) w[k] = (__bf16)acc[k];
        __builtin_nontemporal_store(w, (bf16x8*)((__bf16*)out + (size_t)g * D + dd));
    } else {
        f32x4 lo = {acc[0], acc[1], acc[2], acc[3]};
        f32x4 hi = {acc[4], acc[5], acc[6], acc[7]};
        __builtin_nontemporal_store(lo, (f32x4*)((float*)out + (size_t)g * D + dd));
        __builtin_nontemporal_store(hi, (f32x4*)((float*)out + (size_t)g * D + dd + 4));
    }
}

__global__ __launch_bounds__(256) void edge_agg2_kernel(
    const __bf16* __restrict__ T, const float* __restrict__ G,
    const __bf16* __restrict__ Bz, const float* __restrict__ Bgz,
    const int* __restrict__ rowptr, const int2* __restrict__ recs,
    void* __restrict__ out, int M, const int* __restrict__ flag)
{
    if (flag[0]) edge_agg2_body<1>(T, G, Bz, Bgz, rowptr, recs, out, M);
    else         edge_agg2_body<0>(T, G, Bz, Bgz, rowptr, recs, out, M);
}

__global__ void sentinel_kernel(__bf16* o, int n)
{
    int i = blockIdx.x * blockDim.x + threadIdx.x;
    if (i < n) o[i] = (__bf16)12345.0f;
}

static inline size_t align256(size_t x) { return (x + 255) & ~(size_t)255; }

extern "C" void kernel_launch(void* const* d_in, const int* in_sizes, int n_in,
                              void* d_out, int out_size, void* d_ws, size_t ws_size,
                              hipStream_t stream)
{
    const void* inp       = d_in[0];
    const int*  deprel    = (const int*)d_in[1];
    const int*  deparc    = (const int*)d_in[2];
    const int*  eidx      = (const int*)d_in[3];
    const void* V_in      = d_in[4];
    const void* b_in      = d_in[5];
    const void* V_in_g    = d_in[6];
    const void* b_in_g    = d_in[7];
    const void* V_out     = d_in[8];
    const void* b_out     = d_in[9];
    const void* V_out_g   = d_in[10];
    const void* b_out_g   = d_in[11];
    const void* W_self    = d_in[12];
    const void* W_self_g  = d_in[13];
    const void* W_norel   = d_in[14];
    const void* W_norel_g = d_in[15];

    const int M = in_sizes[0] / D;   // 100000
    const int E = in_sizes[1];       // 600000
    const int* src = eidx;
    const int* tgt = eidx + E;
    const int NB = (M + 1023) / 1024;

    size_t off = 0;
    size_t o_flag   = off; off = align256(off + sizeof(int));
    size_t o_T      = off; off = align256(off + (size_t)M * 4 * D * sizeof(__bf16));
    size_t o_G      = off; off = align256(off + (size_t)4 * M * sizeof(float));
    size_t o_counts = off; off = align256(off + (size_t)M * sizeof(int));
    size_t o_rowptr = off; off = align256(off + (size_t)(M + 1) * sizeof(int));
    size_t o_cursor = off; off = align256(off + (size_t)M * sizeof(int));
    size_t o_bsum   = off; off = align256(off + (size_t)NB * sizeof(int));
    size_t o_recs   = off; off = align256(off + (size_t)E * sizeof(int2));
    size_t o_Bz     = off; off = align256(off + (size_t)101 * D * sizeof(__bf16));
    size_t o_Bgz    = off; off = align256(off + (size_t)101 * sizeof(float));

    if (off > ws_size) {
        sentinel_kernel<<<(out_size + 255) / 256, 256, 0, stream>>>(
            (__bf16*)d_out, out_size);
        return;
    }

    int*    flag   = (int*)((char*)d_ws + o_flag);
    __bf16* T      = (__bf16*)((char*)d_ws + o_T);
    float*  Gbuf   = (float*)((char*)d_ws + o_G);
    int*    counts = (int*)((char*)d_ws + o_counts);
    int*    rowptr = (int*)((char*)d_ws + o_rowptr);
    int*    cursor = (int*)((char*)d_ws + o_cursor);
    int*    bsum   = (int*)((char*)d_ws + o_bsum);
    int2*   recs   = (int2*)((char*)d_ws + o_recs);
    __bf16* Bz     = (__bf16*)((char*)d_ws + o_Bz);
    float*  Bgz    = (float*)((char*)d_ws + o_Bgz);

    // CSR build (detect fused into hist block 0)
    hipMemsetAsync(counts, 0, (size_t)M * sizeof(int), stream);
    hist_detect_kernel<<<(E + 255) / 256, 256, 0, stream>>>(
        tgt, counts, E, (const unsigned int*)inp, flag);
    scan1_kernel<<<NB, 256, 0, stream>>>(counts, rowptr, bsum, M);
    scan3_kernel<<<NB, 256, 0, stream>>>(rowptr, cursor, bsum, M, E);

    // fused: CSR scatter (blocks < NSb) || transform+gates+bias (rest)
    const int ntiles = (M + 127) / 128;
    const int NSb = (((E + 255) / 256) + 7) & ~7;   // multiple of 8: keeps
                                                    // gemm1 sub-grid XCD-aligned
    scatter_gemm1_kernel<<<NSb + ntiles * 4, 256, 0, stream>>>(
        deprel, deparc, src, tgt, cursor, recs, E, NSb,
        inp, V_in, V_out, W_self, W_norel,
        V_in_g, V_out_g, W_self_g, W_norel_g,
        b_in, b_out, b_in_g, b_out_g, T, Gbuf, Bz, Bgz, M, flag);

    // gather-aggregate directly to output
    edge_agg2_kernel<<<(M + 15) / 16, 256, 0, stream>>>(
        T, Gbuf, Bz, Bgz, rowptr, recs, d_out, M, flag);
}